// Round 6
// baseline (2805.705 us; speedup 1.0000x reference)
//
#include <hip/hip_runtime.h>
#include <math.h>

#define BATCH 16
#define NF_ 400
#define TLEN 204800
#define NMELS 80
#define HID 256
#define SRD 44100.0

// ---- compact lifetime-aliased workspace (floats), S = 1,638,400 ----
// ORDER CONSTRAINT: ir_src (reads ssp) MUST run before ir_noise (writes ir3 over ssp).
static constexpr size_t S_ = 1638400;
static constexpr size_t OFF_COMB = 0;          // [0,2S)   comb: phase -> conv1
static constexpr size_t OFF_H1   = 2 * S_;     // [2S,3S)  h1: conv1x3 -> conv2ln
static constexpr size_t OFF_H2   = 3 * S_;     // [3S,4S)  h2: conv2ln -> proj
static constexpr size_t OFF_IR1  = 2 * S_;     // [2S,3.99S) ir1: ir_allpass -> conv1 (h1,h2 dead)
static constexpr size_t OFF_PHI  = 4 * S_;     // [4S,5S)  phi: proj -> ir_allpass
static constexpr size_t OFF_NSP  = 5 * S_;     // [5S,6S)  nsp: proj -> ir_noise
static constexpr size_t OFF_HTMP = 4 * S_;     // [4S,6S)  harmonic tmp: conv1 -> conv2 (phi,nsp dead)
static constexpr size_t OFF_SRC  = 6 * S_;     // [6S,8S)  ssp: proj -> ir_src
static constexpr size_t OFF_IR3  = 6 * S_;     // [6S,7.99S) ir3: ir_noise -> conv3 (ssp dead AFTER ir_src)
static constexpr size_t OFF_IR2  = 8 * S_;     // [8S,11.99S) ir2: ir_src -> conv2
static constexpr size_t OFF_FSUM = 12 * S_;          // 6400 doubles
static constexpr size_t OFF_PREF = 12 * S_ + 12800;  // 6400 doubles
static constexpr size_t OFF_GN   = 12 * S_ + 25600;  // 128 floats
// total: ~78.75 MB

// f0 upsample with JAX's exact f32 rounding: fl(fl(a*(1-w)) + fl(b*w))
__device__ __forceinline__ float cs6_f0_at(const float* f0f, int b, int n, int k) {
    float a = f0f[b * NF_ + n];
    float c = f0f[b * NF_ + min(n + 1, NF_ - 1)];
    float w = (float)k * (1.0f / 512.0f);          // exact
    return __fadd_rn(__fmul_rn(a, 1.0f - w), __fmul_rn(c, w));
}

__global__ void cs6_fsum(const float* __restrict__ f0f, double* __restrict__ fsum) {
    int gid = blockIdx.x * blockDim.x + threadIdx.x;
    if (gid >= BATCH * NF_) return;
    int b = gid / NF_, n = gid % NF_;
    double s = 0.0;
    for (int k = 0; k < 512; ++k) s += (double)cs6_f0_at(f0f, b, n, k) / SRD;
    fsum[gid] = s;
}

__global__ void cs6_prefix(const double* __restrict__ fsum, double* __restrict__ pref) {
    int b = threadIdx.x;
    if (b >= BATCH) return;
    double run = 0.0;
    for (int n = 0; n < NF_; ++n) { pref[b * NF_ + n] = run; run += fsum[b * NF_ + n]; }
}

// per-frame block: f64 inclusive scan of f0/SR -> x, wrap, sinc combtooth + phase output
__global__ __launch_bounds__(512) void cs6_phase(const float* __restrict__ f0f,
        const float* __restrict__ ip, const double* __restrict__ pref,
        float* __restrict__ comb, float* __restrict__ phase_out) {
    __shared__ double sc[512];
    int b = blockIdx.x / NF_, n = blockIdx.x % NF_;
    int k = threadIdx.x;
    float f0 = cs6_f0_at(f0f, b, n, k);
    sc[k] = (double)f0 / SRD;
    __syncthreads();
    for (int off = 1; off < 512; off <<= 1) {
        double v = (k >= off) ? sc[k - off] : 0.0;
        __syncthreads();
        sc[k] += v;
        __syncthreads();
    }
    double xd = pref[b * NF_ + n] + sc[k] + (double)ip[b] / (2.0 * M_PI);
    xd -= rint(xd);                      // round-half-even, matches jnp.round
    float xf = (float)xd;                // reference casts x to f32 before sinc
    double zd = 44100.0 * (double)xf / ((double)f0 + 0.001);
    double pz = M_PI * zd;
    comb[(size_t)b * TLEN + n * 512 + k] = (zd == 0.0) ? 1.0f : (float)(sin(pz) / pz);
    if (k == 0) phase_out[b * NF_ + n] = (float)(2.0 * M_PI * (double)xf);
}

__global__ __launch_bounds__(256) void cs6_conv1x3(const float* __restrict__ mel,
        const float* __restrict__ w1, const float* __restrict__ b1, float* __restrict__ h1) {
    __shared__ float m3[3][NMELS];
    int b = blockIdx.x / NF_, l = blockIdx.x % NF_;
    int tid = threadIdx.x;
    for (int i = tid; i < 3 * NMELS; i += 256) {
        int tap = i / NMELS, ic = i % NMELS;
        int li = l + tap - 1;
        m3[tap][ic] = (li >= 0 && li < NF_) ? mel[((size_t)b * NF_ + li) * NMELS + ic] : 0.0f;
    }
    __syncthreads();
    int oc = tid;
    double acc = (double)b1[oc];
    const float* wp = w1 + (size_t)oc * NMELS * 3;
    for (int ic = 0; ic < NMELS; ++ic)
        acc += (double)m3[0][ic] * (double)wp[ic * 3]
             + (double)m3[1][ic] * (double)wp[ic * 3 + 1]
             + (double)m3[2][ic] * (double)wp[ic * 3 + 2];
    h1[((size_t)b * NF_ + l) * HID + oc] = (float)acc;
}

__global__ __launch_bounds__(256) void cs6_gnstats(const float* __restrict__ h1, float* __restrict__ gn) {
    __shared__ double rs[256], rq[256];
    int b = blockIdx.x >> 2, g = blockIdx.x & 3;
    int tid = threadIdx.x;
    double s = 0.0, q = 0.0;
    for (int i = tid; i < 64 * NF_; i += 256) {
        int l = i >> 6, c = g * 64 + (i & 63);
        float v = h1[((size_t)b * NF_ + l) * HID + c];
        s += v; q += (double)v * v;
    }
    rs[tid] = s; rq[tid] = q;
    __syncthreads();
    for (int off = 128; off > 0; off >>= 1) {
        if (tid < off) { rs[tid] += rs[tid + off]; rq[tid] += rq[tid + off]; }
        __syncthreads();
    }
    if (tid == 0) {
        double mu = rs[0] / (64.0 * NF_);
        double var = rq[0] / (64.0 * NF_) - mu * mu;
        gn[blockIdx.x * 2] = (float)mu;
        gn[blockIdx.x * 2 + 1] = (float)(1.0 / sqrt(var + 1e-5));
    }
}

// GN-affine + lrelu + conv2 + positional-enc + LayerNorm (f64 accumulation), 8 columns per block
__global__ __launch_bounds__(256) void cs6_conv2ln(const float* __restrict__ h1,
        const float* __restrict__ gn, const float* __restrict__ gng, const float* __restrict__ gnb,
        const float* __restrict__ w2, const float* __restrict__ b2,
        const float* __restrict__ pw, const float* __restrict__ pb,
        const float* __restrict__ lng, const float* __restrict__ lnb,
        const float* __restrict__ phase, float* __restrict__ h2) {
    __shared__ float cols[10][HID];
    __shared__ double rsum[256], rsq[256];
    int b = blockIdx.x / 50, l0 = (blockIdx.x % 50) * 8;
    int tid = threadIdx.x;
    for (int i = tid; i < 10 * HID; i += 256) {
        int lc = i >> 8, c = i & 255;
        int l = l0 + lc - 1;
        float v = 0.0f;
        if (l >= 0 && l < NF_) {
            float hv = h1[((size_t)b * NF_ + l) * HID + c];
            int g = c >> 6;
            double vv = ((double)hv - (double)gn[(b * 4 + g) * 2]) * (double)gn[(b * 4 + g) * 2 + 1]
                        * (double)gng[c] + (double)gnb[c];
            v = (float)(vv >= 0.0 ? vv : 0.01 * vv);
        }
        cols[lc][c] = v;
    }
    __syncthreads();
    int oc = tid;
    double acc[8];
    #pragma unroll
    for (int lt = 0; lt < 8; ++lt) acc[lt] = (double)b2[oc];
    const float* wp = w2 + (size_t)oc * HID * 3;
    for (int ic = 0; ic < HID; ++ic) {
        double w0 = (double)wp[ic * 3], w1v = (double)wp[ic * 3 + 1], w2v = (double)wp[ic * 3 + 2];
        float cc[10];
        #pragma unroll
        for (int j = 0; j < 10; ++j) cc[j] = cols[j][ic];   // broadcast reads
        #pragma unroll
        for (int lt = 0; lt < 8; ++lt)
            acc[lt] += (double)cc[lt] * w0 + (double)cc[lt + 1] * w1v + (double)cc[lt + 2] * w2v;
    }
    for (int lt = 0; lt < 8; ++lt) {
        int l = l0 + lt;
        double ph = (double)phase[b * NF_ + l];
        double sp, cp; sincos(ph, &sp, &cp);
        double v = acc[lt] + sp * (double)pw[oc * 2] + cp * (double)pw[oc * 2 + 1] + (double)pb[oc];
        rsum[tid] = v; rsq[tid] = v * v;
        __syncthreads();
        for (int off = 128; off > 0; off >>= 1) {
            if (tid < off) { rsum[tid] += rsum[tid + off]; rsq[tid] += rsq[tid + off]; }
            __syncthreads();
        }
        double mu = rsum[0] * (1.0 / 256.0);
        double var = rsq[0] * (1.0 / 256.0) - mu * mu;
        double rstd = 1.0 / sqrt(var + 1e-5);
        __syncthreads();
        h2[((size_t)b * NF_ + l) * HID + oc] = (float)((v - mu) * rstd * (double)lng[oc] + (double)lnb[oc]);
    }
}

// 1024-wide projection (f64) + split: phi = cumsum(pi*tanh(gd)), exp(hm), exp(nm)/128
__global__ __launch_bounds__(256) void cs6_proj(const float* __restrict__ h2,
        const float* __restrict__ ow, const float* __restrict__ ob,
        float* __restrict__ phi, float* __restrict__ srcspec, float* __restrict__ nspec) {
    __shared__ float hrow[8][HID];
    __shared__ double ssc[256];
    int b = blockIdx.x / 50, l0 = (blockIdx.x % 50) * 8;
    int tid = threadIdx.x;
    for (int i = tid; i < 8 * HID; i += 256) {
        int lc = i >> 8, c = i & 255;
        hrow[lc][c] = h2[((size_t)b * NF_ + l0 + lc) * HID + c];
    }
    __syncthreads();
    double a0[8], a1[8], a2[8], a3[8];
    #pragma unroll
    for (int lt = 0; lt < 8; ++lt) {
        a0[lt] = (double)ob[tid];       a1[lt] = (double)ob[256 + tid];
        a2[lt] = (double)ob[512 + tid]; a3[lt] = (double)ob[768 + tid];
    }
    const float* w0p = ow + (size_t)tid * HID;
    const float* w1p = ow + (size_t)(256 + tid) * HID;
    const float* w2p = ow + (size_t)(512 + tid) * HID;
    const float* w3p = ow + (size_t)(768 + tid) * HID;
    for (int ic = 0; ic < HID; ++ic) {
        double w0 = (double)w0p[ic], w1v = (double)w1p[ic], w2v = (double)w2p[ic], w3v = (double)w3p[ic];
        #pragma unroll
        for (int lt = 0; lt < 8; ++lt) {
            double h = (double)hrow[lt][ic];
            a0[lt] += h * w0; a1[lt] += h * w1v; a2[lt] += h * w2v; a3[lt] += h * w3v;
        }
    }
    for (int lt = 0; lt < 8; ++lt) {
        size_t bl = (size_t)b * NF_ + (l0 + lt);
        double gdv = M_PI * tanh(a0[lt]);
        ssc[tid] = gdv;
        __syncthreads();
        for (int off = 1; off < 256; off <<= 1) {
            double v = (tid >= off) ? ssc[tid - off] : 0.0;
            __syncthreads();
            ssc[tid] += v;
            __syncthreads();
        }
        phi[bl * 256 + tid] = (float)ssc[tid];
        __syncthreads();
        srcspec[bl * 512 + tid] = (float)exp(a1[lt]);
        srcspec[bl * 512 + 256 + tid] = (float)exp(a2[lt]);
        nspec[bl * 256 + tid] = (float)(exp(a3[lt]) * (1.0 / 128.0));
    }
}

// allpass IR: irfft(exp(i*phi)) (510) rolled by 255. f64 rotation recurrence + f64 accum.
__global__ __launch_bounds__(256) void cs6_ir_allpass(const float* __restrict__ phi, float* __restrict__ ir1) {
    __shared__ double cph[256], sph[256];
    size_t bl = blockIdx.x;
    int tid = threadIdx.x;
    {
        double s, c; sincos((double)phi[bl * 256 + tid], &s, &c);
        cph[tid] = 2.0 * c; sph[tid] = 2.0 * s;   // pre-doubled
    }
    __syncthreads();
    for (int t = tid; t < 510; t += 256) {
        double ang = 2.0 * M_PI * (double)t / 510.0;
        double sr, cr; sincos(ang, &sr, &cr);
        double c = cr, s = sr;
        double acc = 0.5 * (cph[0] + ((t & 1) ? -cph[255] : cph[255]));
        for (int k = 1; k <= 254; ++k) {
            acc += cph[k] * c - sph[k] * s;
            double cn = c * cr - s * sr;
            double sn = s * cr + c * sr;
            c = cn; s = sn;
        }
        int j = t + 255; if (j >= 510) j -= 510;
        ir1[bl * 510 + j] = (float)(acc * (1.0 / 510.0));
    }
}

// src IR: irfft(real exp(hm)) (1022), roll 511, half-width window.
// REFERENCE SEMANTICS: w=(j-511)/hw; if (w>1) w:=0 (ARGUMENT zeroed -> window value 1!);
// win=(1+cos(pi*w))/2. Negative tail NOT clamped.
__device__ __forceinline__ double cs6_hw_win(int j, double hw) {
    double wv = (double)(j - 511) / hw;
    if (wv > 1.0) wv = 0.0;
    return (1.0 + cos(M_PI * wv)) * 0.5;
}

__global__ __launch_bounds__(256) void cs6_ir_src(const float* __restrict__ srcspec,
        const float* __restrict__ f0f, float* __restrict__ ir2) {
    __shared__ double sp[512];
    size_t bl = blockIdx.x;
    int b = blockIdx.x / NF_, l = blockIdx.x % NF_;
    int tid = threadIdx.x;
    sp[tid] = 2.0 * (double)srcspec[bl * 512 + tid];
    sp[tid + 256] = 2.0 * (double)srcspec[bl * 512 + 256 + tid];
    __syncthreads();
    double hw = 66150.0 / ((double)f0f[b * NF_ + l] + 0.001);
    for (int t = tid; t < 512; t += 256) {
        double ang = 2.0 * M_PI * (double)t / 1022.0;
        double sr, cr; sincos(ang, &sr, &cr);
        double c = cr, s = sr;
        double acc = 0.5 * (sp[0] + ((t & 1) ? -sp[511] : sp[511]));
        for (int k = 1; k <= 510; ++k) {
            acc += sp[k] * c;
            double cn = c * cr - s * sr;
            double sn = s * cr + c * sr;
            c = cn; s = sn;
        }
        double raw = acc * (1.0 / 1022.0);
        {
            int j = t + 511; if (j >= 1022) j -= 1022;
            ir2[bl * 1022 + j] = (float)(raw * cs6_hw_win(j, hw));
        }
        if (t >= 1 && t <= 510) {          // even symmetry: ir_raw[1022-t] == ir_raw[t]
            int j = 511 - t;
            ir2[bl * 1022 + j] = (float)(raw * cs6_hw_win(j, hw));
        }
    }
}

// noise IR: irfft(real exp(nm)/128) (510): ir[j] = raw[(j-255)%510] * (0.5-0.5cos(2pi j/510)). f64.
__global__ __launch_bounds__(256) void cs6_ir_noise(const float* __restrict__ nspec, float* __restrict__ ir3) {
    __shared__ double sp[256];
    size_t bl = blockIdx.x;
    int t = threadIdx.x;
    sp[t] = 2.0 * (double)nspec[bl * 256 + t];
    __syncthreads();
    double ang = 2.0 * M_PI * (double)t / 510.0;
    double sr, cr; sincos(ang, &sr, &cr);
    double c = cr, s = sr;
    double acc = 0.5 * (sp[0] + ((t & 1) ? -sp[255] : sp[255]));
    for (int k = 1; k <= 254; ++k) {
        acc += sp[k] * c;
        double cn = c * cr - s * sr;
        double sn = s * cr + c * sr;
        c = cn; s = sn;
    }
    double raw = acc * (1.0 / 510.0);
    {
        int j = t + 255; if (j >= 510) j -= 510;
        double win = 0.5 - 0.5 * cos(2.0 * M_PI * (double)j / 510.0);
        ir3[bl * 510 + j] = (float)(raw * win);
    }
    if (t >= 1 && t <= 254) {              // symmetry partner 510-t
        int j = 255 - t;
        double win = 0.5 - 0.5 * cos(2.0 * M_PI * (double)j / 510.0);
        ir3[bl * 510 + j] = (float)(raw * win);
    }
}

// windowed overlap-add convolution, direct time domain (exact vs FFT up to rounding).
// tile = 1024 outputs, 4 outputs/thread, sliding IR register window.
template<int IRS, int NFRM, int MOFF>
__global__ __launch_bounds__(256) void cs6_conv(const float* __restrict__ audio,
        const float* __restrict__ ir, float* __restrict__ out, float scale, float shift) {
    __shared__ float fr[NFRM][1024];
    __shared__ float irp[NFRM][IRS + 8];
    int b = blockIdx.x / 200, q = blockIdx.x % 200;
    int t0 = q * 1024;
    int m_lo = 2 * q + MOFF;
    int tid = threadIdx.x;
    for (int i = tid; i < NFRM * 1024; i += 256) {
        int fi = i >> 10, k = i & 1023;
        int m = m_lo + fi;
        int idx = (m << 9) + k - 512;
        float v = 0.0f;
        if (m >= 0 && m <= 400 && idx >= 0 && idx < TLEN)
            v = audio[(size_t)b * TLEN + idx] * scale + shift;
        float bart = 1.0f - fabsf((float)k * (1.0f / 512.0f) - 1.0f);
        fr[fi][k] = v * bart;
    }
    for (int i = tid; i < NFRM * (IRS + 8); i += 256) {
        int fi = i / (IRS + 8), j = i % (IRS + 8);
        int jj = j - 4;
        int m = m_lo + fi;
        float v = 0.0f;
        if (jj >= 0 && jj < IRS && m >= 0 && m <= 400)
            v = ir[((size_t)b * NF_ + min(m, 399)) * IRS + jj];
        irp[fi][j] = v;
    }
    __syncthreads();
    int tb = t0 + tid * 4;
    int s0 = tb + 512;
    float acc0 = 0, acc1 = 0, acc2 = 0, acc3 = 0;
    #pragma unroll
    for (int fi = 0; fi < NFRM; ++fi) {
        int m = m_lo + fi;
        if (m < 0 || m > 400) continue;
        int d0 = s0 - (m << 9);
        int k_lo = max(0, d0 - (IRS - 1));
        int k_hi = min(1023, d0 + 3);
        if (k_lo > k_hi) continue;
        const float* irow = &irp[fi][4];
        int jb = d0 - k_lo;
        float w1v = irow[jb + 1], w2v = irow[jb + 2], w3v = irow[jb + 3];
        for (int k = k_lo; k <= k_hi; ++k) {
            float w0v = irow[d0 - k];
            float f = fr[fi][k];
            acc0 += f * w0v; acc1 += f * w1v; acc2 += f * w2v; acc3 += f * w3v;
            w3v = w2v; w2v = w1v; w1v = w0v;
        }
    }
    *(float4*)(out + (size_t)b * TLEN + tb) = make_float4(acc0, acc1, acc2, acc3);
}

__global__ void cs6_add(const float* __restrict__ a, const float* __restrict__ b,
                        float* __restrict__ o, int n4) {
    int i = blockIdx.x * blockDim.x + threadIdx.x;
    if (i < n4) {
        float4 x = ((const float4*)a)[i];
        float4 y = ((const float4*)b)[i];
        ((float4*)o)[i] = make_float4(x.x + y.x, x.y + y.y, x.z + y.z, x.w + y.w);
    }
}

extern "C" void kernel_launch(void* const* d_in, const int* in_sizes, int n_in,
                              void* d_out, int out_size, void* d_ws, size_t ws_size,
                              hipStream_t stream) {
    const float* mel   = (const float*)d_in[0];
    const float* f0f   = (const float*)d_in[1];
    const float* ip    = (const float*)d_in[2];
    const float* unoi  = (const float*)d_in[3];
    const float* w1    = (const float*)d_in[4];
    const float* b1    = (const float*)d_in[5];
    const float* gng   = (const float*)d_in[6];
    const float* gnb   = (const float*)d_in[7];
    const float* w2    = (const float*)d_in[8];
    const float* b2    = (const float*)d_in[9];
    const float* pw    = (const float*)d_in[10];
    const float* pb    = (const float*)d_in[11];
    const float* lng   = (const float*)d_in[12];
    const float* lnb   = (const float*)d_in[13];
    const float* ow    = (const float*)d_in[14];
    const float* ob    = (const float*)d_in[15];
    float* out = (float*)d_out;
    float* ws  = (float*)d_ws;

    float*  comb = ws + OFF_COMB;
    float*  h1   = ws + OFF_H1;
    float*  h2   = ws + OFF_H2;
    float*  ir1  = ws + OFF_IR1;
    float*  phi  = ws + OFF_PHI;
    float*  nsp  = ws + OFF_NSP;
    float*  htmp = ws + OFF_HTMP;
    float*  ssp  = ws + OFF_SRC;
    float*  ir3  = ws + OFF_IR3;
    float*  ir2  = ws + OFF_IR2;
    double* fsum = (double*)(ws + OFF_FSUM);
    double* pref = (double*)(ws + OFF_PREF);
    float*  gn   = ws + OFF_GN;

    float* out_sig   = out;
    float* out_phase = out + (size_t)BATCH * TLEN;
    float* out_harm  = out_phase + BATCH * NF_;
    float* out_noise = out_harm + (size_t)BATCH * TLEN;

    cs6_fsum<<<25, 256, 0, stream>>>(f0f, fsum);
    cs6_prefix<<<1, 16, 0, stream>>>(fsum, pref);
    cs6_phase<<<BATCH * NF_, 512, 0, stream>>>(f0f, ip, pref, comb, out_phase);
    cs6_conv1x3<<<BATCH * NF_, 256, 0, stream>>>(mel, w1, b1, h1);
    cs6_gnstats<<<64, 256, 0, stream>>>(h1, gn);
    cs6_conv2ln<<<BATCH * 50, 256, 0, stream>>>(h1, gn, gng, gnb, w2, b2, pw, pb, lng, lnb, out_phase, h2);
    cs6_proj<<<BATCH * 50, 256, 0, stream>>>(h2, ow, ob, phi, ssp, nsp);
    cs6_ir_allpass<<<BATCH * NF_, 256, 0, stream>>>(phi, ir1);
    cs6_ir_src<<<BATCH * NF_, 256, 0, stream>>>(ssp, f0f, ir2);      // MUST precede ir_noise (ssp/ir3 alias)
    cs6_ir_noise<<<BATCH * NF_, 256, 0, stream>>>(nsp, ir3);
    cs6_conv<510, 4, -1><<<BATCH * 200, 256, 0, stream>>>(comb, ir1, htmp, 1.0f, 0.0f);
    cs6_conv<1022, 5, -2><<<BATCH * 200, 256, 0, stream>>>(htmp, ir2, out_harm, 1.0f, 0.0f);
    cs6_conv<510, 4, -1><<<BATCH * 200, 256, 0, stream>>>(unoi, ir3, out_noise, 2.0f, -1.0f);
    cs6_add<<<(BATCH * TLEN / 4 + 255) / 256, 256, 0, stream>>>(out_harm, out_noise, out_sig, BATCH * TLEN / 4);
}